// Round 2
// baseline (893.180 us; speedup 1.0000x reference)
//
#include <hip/hip_runtime.h>
#include <cstdint>

#define DD     1024
#define NINNER 4096
#define NTOK   32768   // B*T = 8*4096
#define MROWS  8192    // tokens per expert

typedef unsigned short u16;
typedef __bf16 bf16x8 __attribute__((ext_vector_type(8)));
typedef float  f32x4  __attribute__((ext_vector_type(4)));

// fp32 -> bf16 round-to-nearest-even
__device__ __forceinline__ u16 f2bf(float f) {
    union { float f; uint32_t u; } a; a.f = f;
    uint32_t r = a.u + 0x7fffu + ((a.u >> 16) & 1u);
    return (u16)(r >> 16);
}

// async global->LDS, 16B per lane; LDS dest = wave-uniform base + lane*16
__device__ __forceinline__ void async16(const void* g, void* l) {
    __builtin_amdgcn_global_load_lds(
        (const __attribute__((address_space(1))) void*)g,
        (__attribute__((address_space(3))) void*)l,
        16, 0, 0);
}

#define BARRIER() do { asm volatile("" ::: "memory");              \
                       __builtin_amdgcn_s_barrier();               \
                       asm volatile("" ::: "memory"); } while (0)

// ---------------- weight cast: fp32 -> bf16 ----------------
__global__ __launch_bounds__(256) void cast_w(
    const float* __restrict__ w1, const float* __restrict__ w2,
    u16* __restrict__ w1b, u16* __restrict__ w2b)
{
    int idx = blockIdx.x * 256 + threadIdx.x;     // float4 index
    const int n1 = (NINNER * DD) / 4;             // 1M float4 in l1_w
    float4 v; ushort4 o;
    if (idx < n1) {
        v = ((const float4*)w1)[idx];
        o.x = f2bf(v.x); o.y = f2bf(v.y); o.z = f2bf(v.z); o.w = f2bf(v.w);
        ((ushort4*)w1b)[idx] = o;
    } else {
        int j = idx - n1;
        v = ((const float4*)w2)[j];
        o.x = f2bf(v.x); o.y = f2bf(v.y); o.z = f2bf(v.z); o.w = f2bf(v.w);
        ((ushort4*)w2b)[j] = o;
    }
}

// ---------------- LayerNorm -> bf16 h, plus FULL out init ----------------
// out[:, :m] = x + sc*l2b   (gemm2 adds sc*acc on top, exclusive owner per tile)
// out[:, m:] = x            (pad region)
__global__ __launch_bounds__(256) void ln_kernel(
    const float* __restrict__ x, const float* __restrict__ nw,
    const float* __restrict__ nb, const float* __restrict__ l2b,
    const float* __restrict__ rp, const float* __restrict__ alphap,
    u16* __restrict__ h, float* __restrict__ out)
{
    const int row = blockIdx.x;          // 0..32767 global token
    const int tid = threadIdx.x;
    const float4 v = ((const float4*)(x + (size_t)row * DD))[tid];
    float s  = v.x + v.y + v.z + v.w;
    float s2 = v.x*v.x + v.y*v.y + v.z*v.z + v.w*v.w;
#pragma unroll
    for (int o = 32; o > 0; o >>= 1) {
        s  += __shfl_down(s,  o, 64);
        s2 += __shfl_down(s2, o, 64);
    }
    __shared__ float as1[4], as2[4];
    if ((tid & 63) == 0) { as1[tid >> 6] = s; as2[tid >> 6] = s2; }
    __syncthreads();
    const float S  = as1[0] + as1[1] + as1[2] + as1[3];
    const float S2 = as2[0] + as2[1] + as2[2] + as2[3];
    const float mu  = S  * (1.0f / 1024.0f);
    const float var = S2 * (1.0f / 1024.0f) - mu * mu;
    const float rs  = rsqrtf(var + 1e-5f);
    const float4 w4 = ((const float4*)nw)[tid];
    const float4 b4 = ((const float4*)nb)[tid];
    ushort4 hv;
    hv.x = f2bf((v.x - mu) * rs * w4.x + b4.x);
    hv.y = f2bf((v.y - mu) * rs * w4.y + b4.y);
    hv.z = f2bf((v.z - mu) * rs * w4.z + b4.z);
    hv.w = f2bf((v.w - mu) * rs * w4.w + b4.w);
    ((ushort4*)(h + (size_t)row * DD))[tid] = hv;

    const int e = (row >> 10) & 3;
    const int m = DD >> e;
    float4 o4;
    if (tid * 4 < m) {
        const float sc = alphap[0] * rp[(size_t)row * 4 + e] + 1.0f;
        const float4 lb = ((const float4*)l2b)[tid];
        o4.x = v.x + sc * lb.x; o4.y = v.y + sc * lb.y;
        o4.z = v.z + sc * lb.z; o4.w = v.w + sc * lb.w;
    } else {
        o4 = v;
    }
    ((float4*)(out + (size_t)row * DD))[tid] = o4;
}

// ---------------- 128x128 GEMM1 (kept for e=2,3: K=256,128) ----------------
__global__ __launch_bounds__(256) void gemm1(
    const u16* __restrict__ h, const u16* __restrict__ w1b,
    const float* __restrict__ l1b, u16* __restrict__ inner,
    int K, int e)
{
    __shared__ __align__(16) u16 lA[128 * 64];
    __shared__ __align__(16) u16 lB[128 * 64];
    const int tid  = threadIdx.x;
    const int lane = tid & 63;
    const int w    = tid >> 6;
    const int wr   = w >> 1, wc = w & 1;
    const int bm = blockIdx.y, bn = blockIdx.x;

    f32x4 acc[4][4] = {};

    const int srow = (lane >> 3);
    const int soff = ((lane & 7) ^ srow) * 8;

    for (int kt = 0; kt < K; kt += 64) {
#pragma unroll
        for (int i = 0; i < 4; ++i) {
            const int c   = w * 4 + i;
            const int row = c * 8 + srow;
            const int rl  = bm * 128 + row;
            const int g   = ((rl >> 10) << 12) + (e << 10) + (rl & 1023);
            async16(h + (size_t)g * DD + kt + soff, &lA[c * 512]);
        }
#pragma unroll
        for (int i = 0; i < 4; ++i) {
            const int c   = w * 4 + i;
            const int row = c * 8 + srow;
            async16(w1b + (size_t)(bn * 128 + row) * DD + kt + soff, &lB[c * 512]);
        }
        __syncthreads();
#pragma unroll
        for (int kk = 0; kk < 2; ++kk) {
            const int sg = ((kk * 4 + (lane >> 4)) ^ (lane & 7)) * 8;
            bf16x8 af[4], bq[4];
#pragma unroll
            for (int i = 0; i < 4; ++i)
                af[i] = *(const bf16x8*)&lA[(wr * 64 + i * 16 + (lane & 15)) * 64 + sg];
#pragma unroll
            for (int i = 0; i < 4; ++i)
                bq[i] = *(const bf16x8*)&lB[(wc * 64 + i * 16 + (lane & 15)) * 64 + sg];
#pragma unroll
            for (int mi = 0; mi < 4; ++mi)
#pragma unroll
                for (int ni = 0; ni < 4; ++ni)
                    acc[mi][ni] = __builtin_amdgcn_mfma_f32_16x16x32_bf16(
                        af[mi], bq[ni], acc[mi][ni], 0, 0, 0);
        }
        __syncthreads();
    }

    const int cbase = bn * 128 + wc * 64 + (lane & 15);
    const int rbase = bm * 128 + wr * 64 + (lane >> 4) * 4;
#pragma unroll
    for (int ni = 0; ni < 4; ++ni) {
        const int col = cbase + ni * 16;
        const float bias = l1b[col];
#pragma unroll
        for (int mi = 0; mi < 4; ++mi) {
            const int r0 = rbase + mi * 16;
#pragma unroll
            for (int r = 0; r < 4; ++r) {
                const float vv = acc[mi][ni][r] + bias;
                const float gg = 0.5f * vv * (1.0f + erff(vv * 0.7071067811865476f));
                inner[(size_t)(r0 + r) * NINNER + col] = f2bf(gg);
            }
        }
    }
}

// ================= 256x256 8-wave 3-phase pipelined GEMM1 =================
// Per K-tile (BK=64): ALL 8 loads for tile t+1 issued at ph1-top (order
// A0,B0,B1,A1), then 3 phases:
//  ph1: read A0-frags + B0-frags, MFMA quad(0,0);  gate vmcnt(10) [retire B1 of t]
//  ph2: read B1-frags,            MFMA quad(0,1);  gate vmcnt(8)  [retire A1 of t]
//  ph3: read A1 + B0, MFMA quad(1,0); read B1, MFMA quad(1,1);
//                                                  gate vmcnt(4)  [retire A0,B0 of t+1]
// Every load has 4-6 phases of slack before its gate (covers ~900cy HBM).
// One barrier after each gate publishes retirement across waves.
__global__ __launch_bounds__(512, 2) void gemm1_big(
    const u16* __restrict__ h, const u16* __restrict__ w1b,
    const float* __restrict__ l1b, u16* __restrict__ inner,
    int K, int e)
{
    __shared__ __align__(16) u16 lA[2][2][8192];   // [buf][half][128*64]
    __shared__ __align__(16) u16 lB[2][2][8192];
    const int tid  = threadIdx.x;
    const int lane = tid & 63;
    const int w    = tid >> 6;          // 0..7
    const int qr   = w >> 2;            // 0..1
    const int qc   = w & 3;             // 0..3
    const int l15  = lane & 15, l4g = lane >> 4, l7 = lane & 7;
    const int lrow = lane >> 3;
    const int soff = (l7 ^ lrow) * 8;

    // XCD-chunked swizzle over 512 blocks (32 bm x 16 bn)
    const int id  = blockIdx.x;
    const int swz = (id & 7) * 64 + (id >> 3);
    const int bm  = swz >> 4, bn = swz & 15;

    const int NT = K >> 6;

    // loop-invariant stage source offsets (u16 index), add kt at issue
    size_t aOff[2][2], bOff[2][2];
#pragma unroll
    for (int hf = 0; hf < 2; ++hf)
#pragma unroll
        for (int i = 0; i < 2; ++i) {
            const int c  = i * 8 + w;
            const int rl = bm * 256 + hf * 128 + c * 8 + lrow;
            const int g  = ((rl >> 10) << 12) + (e << 10) + (rl & 1023);
            aOff[hf][i]  = (size_t)g * DD + soff;
            const int rb = bn * 256 + hf * 128 + c * 8 + lrow;
            bOff[hf][i]  = (size_t)rb * DD + soff;
        }

    f32x4 acc[4][4][2] = {};
    bf16x8 af[4][2], bq[2][2];

    auto STAGE_ALL = [&](int buf, int kt) {
        // issue order A0,B0,B1,A1 — gate arithmetic depends on it
        async16(h   + aOff[0][0] + kt, &lA[buf][0][w * 512]);
        async16(h   + aOff[0][1] + kt, &lA[buf][0][(8 + w) * 512]);
        async16(w1b + bOff[0][0] + kt, &lB[buf][0][w * 512]);
        async16(w1b + bOff[0][1] + kt, &lB[buf][0][(8 + w) * 512]);
        async16(w1b + bOff[1][0] + kt, &lB[buf][1][w * 512]);
        async16(w1b + bOff[1][1] + kt, &lB[buf][1][(8 + w) * 512]);
        async16(h   + aOff[1][0] + kt, &lA[buf][1][w * 512]);
        async16(h   + aOff[1][1] + kt, &lA[buf][1][(8 + w) * 512]);
    };
    auto DSA = [&](int buf, int half) {
#pragma unroll
        for (int mi = 0; mi < 4; ++mi)
#pragma unroll
            for (int kk = 0; kk < 2; ++kk)
                af[mi][kk] = *(const bf16x8*)&lA[buf][half]
                    [(qr * 64 + mi * 16 + l15) * 64 + ((kk * 4 + l4g) ^ l7) * 8];
    };
    auto DSB = [&](int buf, int half) {
#pragma unroll
        for (int ni = 0; ni < 2; ++ni)
#pragma unroll
            for (int kk = 0; kk < 2; ++kk)
                bq[ni][kk] = *(const bf16x8*)&lB[buf][half]
                    [(qc * 32 + ni * 16 + l15) * 64 + ((kk * 4 + l4g) ^ l7) * 8];
    };
    auto MM = [&](f32x4 (&ac)[4][2]) {
#pragma unroll
        for (int mi = 0; mi < 4; ++mi)
#pragma unroll
            for (int ni = 0; ni < 2; ++ni) {
                f32x4 c = ac[mi][ni];
                c = __builtin_amdgcn_mfma_f32_16x16x32_bf16(af[mi][0], bq[ni][0], c, 0, 0, 0);
                c = __builtin_amdgcn_mfma_f32_16x16x32_bf16(af[mi][1], bq[ni][1], c, 0, 0, 0);
                ac[mi][ni] = c;
            }
    };

    // prologue: tile 0 into buf0; retire A0,B0 (keep B1,A1 in flight)
    STAGE_ALL(0, 0);
    asm volatile("s_waitcnt vmcnt(4)" ::: "memory");
    BARRIER();

    for (int t = 0; t < NT; ++t) {
        const int cur = t & 1, nxt = cur ^ 1;
        const int kn  = (t + 1 < NT ? t + 1 : t) << 6;   // tail: dummy re-stage keeps counts
        // ---- ph1: quad (0,0)
        STAGE_ALL(nxt, kn);
        DSA(cur, 0);
        DSB(cur, 0);
        __builtin_amdgcn_s_setprio(1);
        MM(acc[0]);
        __builtin_amdgcn_s_setprio(0);
        asm volatile("s_waitcnt vmcnt(10)" ::: "memory");
        BARRIER();
        // ---- ph2: quad (0,1)  (af = A-half0 reused)
        DSB(cur, 1);
        __builtin_amdgcn_s_setprio(1);
        MM(acc[1]);
        __builtin_amdgcn_s_setprio(0);
        asm volatile("s_waitcnt vmcnt(8)" ::: "memory");
        BARRIER();
        // ---- ph3: quads (1,0) and (1,1)
        DSA(cur, 1);
        DSB(cur, 0);
        __builtin_amdgcn_s_setprio(1);
        MM(acc[2]);
        __builtin_amdgcn_s_setprio(0);
        DSB(cur, 1);
        __builtin_amdgcn_s_setprio(1);
        MM(acc[3]);
        __builtin_amdgcn_s_setprio(0);
        asm volatile("s_waitcnt vmcnt(4)" ::: "memory");
        BARRIER();
    }

    // epilogue: bias + exact GELU -> bf16
#pragma unroll
    for (int nh = 0; nh < 2; ++nh) {
#pragma unroll
        for (int ni = 0; ni < 2; ++ni) {
            const int col  = bn * 256 + nh * 128 + qc * 32 + ni * 16 + l15;
            const float bias = l1b[col];
#pragma unroll
            for (int mh = 0; mh < 2; ++mh) {
                const int rb = bm * 256 + mh * 128 + qr * 64 + l4g * 4;
#pragma unroll
                for (int mi = 0; mi < 4; ++mi) {
#pragma unroll
                    for (int r = 0; r < 4; ++r) {
                        const float vv = acc[mh * 2 + nh][mi][ni][r] + bias;
                        const float gg = 0.5f * vv * (1.0f + erff(vv * 0.7071067811865476f));
                        inner[(size_t)(rb + mi * 16 + r) * NINNER + col] = f2bf(gg);
                    }
                }
            }
        }
    }
}

// ============== GEMM2: full-K, NO atomics, block owns its output tile ==============
// out[g, col] += sc * (inner[rl,:] . w2b[col,:])   — plain RMW, exclusive owner.
// Tile BM x 128, K = NINNER (full). Per-wave 64x64 output: 32 MFMA : 16 ds_read_b128
// per K-tile. All loads for tile t+NBUF-1 issued at tile-top; one counted vmcnt gate
// + one barrier per tile. NBUF=3 gives 2-tile (~>1400cy) load slack.
// Grid decode: xcd = id&7; j = id>>3; bm = ((j>>lgBn)<<3)|xcd; bn = j & (2^lgBn-1)
// -> all bn-blocks of one bm share an XCD slot (A-panel stays in one L2).
template<int BM, int NBUF>
__global__ __launch_bounds__(BM * 2, 2) void gemm2_nk(
    const u16* __restrict__ inner, const u16* __restrict__ w2b,
    const float* __restrict__ rp, const float* __restrict__ alphap,
    float* __restrict__ out, int e, int lgBn)
{
    constexpr int WAVES = BM / 32;          // 8 / 4 / 2
    constexpr int LB    = 512 / BM;         // B loads per wave: 2 / 4 / 8
    constexpr int NT    = NINNER / 64;      // 64 K-tiles (K always 4096)

    __shared__ __align__(16) u16 lA[NBUF][BM * 64];
    __shared__ __align__(16) u16 lB[NBUF][128 * 64];

    const int tid  = threadIdx.x;
    const int lane = tid & 63;
    const int w    = tid >> 6;
    const int wr   = w >> 1, wc = w & 1;    // wave grid (WAVES/2) x 2, 64x64 each
    const int l15  = lane & 15, l4g = lane >> 4, l7 = lane & 7;
    const int lrow = lane >> 3;
    const int soff = (l7 ^ lrow) * 8;

    const int id  = blockIdx.x;
    const int xcd = id & 7, j = id >> 3;
    const int bm  = ((j >> lgBn) << 3) | xcd;
    const int bn  = j & ((1 << lgBn) - 1);

    size_t aOff[4], bOff[LB];
#pragma unroll
    for (int i = 0; i < 4; ++i) {
        const int row = bm * BM + (i * WAVES + w) * 8 + lrow;
        aOff[i] = (size_t)row * NINNER + soff;
    }
#pragma unroll
    for (int i = 0; i < LB; ++i) {
        const int row = bn * 128 + (i * WAVES + w) * 8 + lrow;
        bOff[i] = (size_t)row * NINNER + soff;
    }

    auto STAGE = [&](int buf, int kt) {
#pragma unroll
        for (int i = 0; i < 4; ++i)
            async16(inner + aOff[i] + kt, &lA[buf][(i * WAVES + w) * 512]);
#pragma unroll
        for (int i = 0; i < LB; ++i)
            async16(w2b + bOff[i] + kt, &lB[buf][(i * WAVES + w) * 512]);
    };

    f32x4 acc[4][4] = {};
    bf16x8 af[4][2], bq[4][2];

    // prologue
    STAGE(0, 0);
    if constexpr (NBUF == 3) STAGE(1, 64);
    if constexpr (BM == 256)      asm volatile("s_waitcnt vmcnt(6)"  ::: "memory");
    else if constexpr (BM == 64)  asm volatile("s_waitcnt vmcnt(12)" ::: "memory");
    else                          asm volatile("s_waitcnt vmcnt(0)"  ::: "memory");
    BARRIER();

    int cur = 0, stg = NBUF - 1;
    for (int t = 0; t < NT; ++t) {
        const int ts = (t + NBUF - 1 < NT ? t + NBUF - 1 : NT - 1);
        STAGE(stg, ts * 64);
#pragma unroll
        for (int mi = 0; mi < 4; ++mi)
#pragma unroll
            for (int kk = 0; kk < 2; ++kk)
                af[mi][kk] = *(const bf16x8*)&lA[cur]
                    [(wr * 64 + mi * 16 + l15) * 64 + ((kk * 4 + l4g) ^ l7) * 8];
#pragma unroll
        for (int ni = 0; ni < 4; ++ni)
#pragma unroll
            for (int kk = 0; kk < 2; ++kk)
                bq[ni][kk] = *(const bf16x8*)&lB[cur]
                    [(wc * 64 + ni * 16 + l15) * 64 + ((kk * 4 + l4g) ^ l7) * 8];
        __builtin_amdgcn_s_setprio(1);
#pragma unroll
        for (int mi = 0; mi < 4; ++mi)
#pragma unroll
            for (int ni = 0; ni < 4; ++ni) {
                f32x4 c = acc[mi][ni];
                c = __builtin_amdgcn_mfma_f32_16x16x32_bf16(af[mi][0], bq[ni][0], c, 0, 0, 0);
                c = __builtin_amdgcn_mfma_f32_16x16x32_bf16(af[mi][1], bq[ni][1], c, 0, 0, 0);
                acc[mi][ni] = c;
            }
        __builtin_amdgcn_s_setprio(0);
        if constexpr (BM == 256)      asm volatile("s_waitcnt vmcnt(6)"  ::: "memory");
        else if constexpr (BM == 64)  asm volatile("s_waitcnt vmcnt(12)" ::: "memory");
        else                          asm volatile("s_waitcnt vmcnt(0)"  ::: "memory");
        BARRIER();
        cur = (cur + 1 == NBUF) ? 0 : cur + 1;
        stg = (stg + 1 == NBUF) ? 0 : stg + 1;
    }

    // epilogue: plain RMW (exclusive tile ownership — no atomics)
    const float alpha = alphap[0];
#pragma unroll
    for (int mi = 0; mi < 4; ++mi) {
#pragma unroll
        for (int r = 0; r < 4; ++r) {
            const int rl = bm * BM + wr * 64 + mi * 16 + l4g * 4 + r;
            const int g  = ((rl >> 10) << 12) + (e << 10) + (rl & 1023);
            const float sc = alpha * rp[(size_t)g * 4 + e] + 1.0f;
            float* po = out + (size_t)g * DD;
#pragma unroll
            for (int ni = 0; ni < 4; ++ni) {
                const int col = bn * 128 + wc * 64 + ni * 16 + l15;
                po[col] += sc * acc[mi][ni][r];
            }
        }
    }
}

extern "C" void kernel_launch(void* const* d_in, const int* in_sizes, int n_in,
                              void* d_out, int out_size, void* d_ws, size_t ws_size,
                              hipStream_t stream) {
    const float* x     = (const float*)d_in[0];
    const float* rp    = (const float*)d_in[1];
    const float* alpha = (const float*)d_in[2];
    const float* nw    = (const float*)d_in[3];
    const float* nb    = (const float*)d_in[4];
    const float* l1w   = (const float*)d_in[5];
    const float* l1b   = (const float*)d_in[6];
    const float* l2w   = (const float*)d_in[7];
    const float* l2b   = (const float*)d_in[8];
    float* out = (float*)d_out;

    // workspace layout: h (64MB) | inner (64MB) | w1b (8MB) | w2b (8MB)
    char* ws = (char*)d_ws;
    if (ws_size < ((size_t)144 << 20)) return;
    u16* h     = (u16*)(ws);
    u16* inner = (u16*)(ws + ((size_t)64 << 20));
    u16* w1b   = (u16*)(ws + ((size_t)128 << 20));
    u16* w2b   = (u16*)(ws + ((size_t)136 << 20));

    cast_w<<<8192, 256, 0, stream>>>(l1w, l2w, w1b, w2b);
    ln_kernel<<<NTOK, 256, 0, stream>>>(x, nw, nb, l2b, rp, alpha, h, out);
    for (int e = 0; e < 4; ++e) {
        const int m = DD >> e;
        if (e < 2)
            gemm1_big<<<512, 512, 0, stream>>>(h, w1b, l1b, inner, m, e);
        else
            gemm1<<<dim3(NINNER / 128, MROWS / 128), 256, 0, stream>>>(h, w1b, l1b, inner, m, e);
        switch (e) {
            case 0: gemm2_nk<256, 3><<<256, 512, 0, stream>>>(inner, w2b, rp, alpha, out, e, 3); break;
            case 1: gemm2_nk<128, 2><<<256, 256, 0, stream>>>(inner, w2b, rp, alpha, out, e, 2); break;
            case 2: gemm2_nk< 64, 3><<<256, 128, 0, stream>>>(inner, w2b, rp, alpha, out, e, 1); break;
            case 3: gemm2_nk< 64, 3><<<128, 128, 0, stream>>>(inner, w2b, rp, alpha, out, e, 0); break;
        }
    }
}

// Round 3
// 855.338 us; speedup vs baseline: 1.0442x; 1.0442x over previous
//
#include <hip/hip_runtime.h>
#include <cstdint>

#define DD     1024
#define NINNER 4096
#define NTOK   32768   // B*T = 8*4096
#define MROWS  8192    // tokens per expert

typedef unsigned short u16;
typedef __bf16 bf16x8 __attribute__((ext_vector_type(8)));
typedef float  f32x4  __attribute__((ext_vector_type(4)));

// fp32 -> bf16 round-to-nearest-even
__device__ __forceinline__ u16 f2bf(float f) {
    union { float f; uint32_t u; } a; a.f = f;
    uint32_t r = a.u + 0x7fffu + ((a.u >> 16) & 1u);
    return (u16)(r >> 16);
}

// exact-enough GELU: erf via A&S 7.1.26 (|err| <= 1.5e-7), ~14 VALU vs erff's ~40+
__device__ __forceinline__ float gelu_f(float v) {
    const float xs = v * 0.7071067811865476f;
    const float ax = fabsf(xs);
    const float t  = 1.0f / (1.0f + 0.3275911f * ax);
    float p = 1.061405429f;
    p = fmaf(p, t, -1.453152027f);
    p = fmaf(p, t,  1.421413741f);
    p = fmaf(p, t, -0.284496736f);
    p = fmaf(p, t,  0.254829592f);
    const float er = 1.0f - p * t * __expf(-ax * ax);
    const float erf_xs = (xs < 0.0f) ? -er : er;
    return 0.5f * v * (1.0f + erf_xs);
}

// async global->LDS, 16B per lane; LDS dest = wave-uniform base + lane*16
__device__ __forceinline__ void async16(const void* g, void* l) {
    __builtin_amdgcn_global_load_lds(
        (const __attribute__((address_space(1))) void*)g,
        (__attribute__((address_space(3))) void*)l,
        16, 0, 0);
}

#define BARRIER() do { asm volatile("" ::: "memory");              \
                       __builtin_amdgcn_s_barrier();               \
                       asm volatile("" ::: "memory"); } while (0)

// ---------------- weight cast: fp32 -> bf16 ----------------
__global__ __launch_bounds__(256) void cast_w(
    const float* __restrict__ w1, const float* __restrict__ w2,
    u16* __restrict__ w1b, u16* __restrict__ w2b)
{
    int idx = blockIdx.x * 256 + threadIdx.x;     // float4 index
    const int n1 = (NINNER * DD) / 4;             // 1M float4 in l1_w
    float4 v; ushort4 o;
    if (idx < n1) {
        v = ((const float4*)w1)[idx];
        o.x = f2bf(v.x); o.y = f2bf(v.y); o.z = f2bf(v.z); o.w = f2bf(v.w);
        ((ushort4*)w1b)[idx] = o;
    } else {
        int j = idx - n1;
        v = ((const float4*)w2)[j];
        o.x = f2bf(v.x); o.y = f2bf(v.y); o.z = f2bf(v.z); o.w = f2bf(v.w);
        ((ushort4*)w2b)[j] = o;
    }
}

// ---------------- LayerNorm -> bf16 h, plus FULL out init ----------------
__global__ __launch_bounds__(256) void ln_kernel(
    const float* __restrict__ x, const float* __restrict__ nw,
    const float* __restrict__ nb, const float* __restrict__ l2b,
    const float* __restrict__ rp, const float* __restrict__ alphap,
    u16* __restrict__ h, float* __restrict__ out)
{
    const int row = blockIdx.x;          // 0..32767 global token
    const int tid = threadIdx.x;
    const float4 v = ((const float4*)(x + (size_t)row * DD))[tid];
    float s  = v.x + v.y + v.z + v.w;
    float s2 = v.x*v.x + v.y*v.y + v.z*v.z + v.w*v.w;
#pragma unroll
    for (int o = 32; o > 0; o >>= 1) {
        s  += __shfl_down(s,  o, 64);
        s2 += __shfl_down(s2, o, 64);
    }
    __shared__ float as1[4], as2[4];
    if ((tid & 63) == 0) { as1[tid >> 6] = s; as2[tid >> 6] = s2; }
    __syncthreads();
    const float S  = as1[0] + as1[1] + as1[2] + as1[3];
    const float S2 = as2[0] + as2[1] + as2[2] + as2[3];
    const float mu  = S  * (1.0f / 1024.0f);
    const float var = S2 * (1.0f / 1024.0f) - mu * mu;
    const float rs  = rsqrtf(var + 1e-5f);
    const float4 w4 = ((const float4*)nw)[tid];
    const float4 b4 = ((const float4*)nb)[tid];
    ushort4 hv;
    hv.x = f2bf((v.x - mu) * rs * w4.x + b4.x);
    hv.y = f2bf((v.y - mu) * rs * w4.y + b4.y);
    hv.z = f2bf((v.z - mu) * rs * w4.z + b4.z);
    hv.w = f2bf((v.w - mu) * rs * w4.w + b4.w);
    ((ushort4*)(h + (size_t)row * DD))[tid] = hv;

    const int e = (row >> 10) & 3;
    const int m = DD >> e;
    float4 o4;
    if (tid * 4 < m) {
        const float sc = alphap[0] * rp[(size_t)row * 4 + e] + 1.0f;
        const float4 lb = ((const float4*)l2b)[tid];
        o4.x = v.x + sc * lb.x; o4.y = v.y + sc * lb.y;
        o4.z = v.z + sc * lb.z; o4.w = v.w + sc * lb.w;
    } else {
        o4 = v;
    }
    ((float4*)(out + (size_t)row * DD))[tid] = o4;
}

// ---------------- 128x128 GEMM1 (kept for e=2,3: K=256,128) ----------------
__global__ __launch_bounds__(256) void gemm1(
    const u16* __restrict__ h, const u16* __restrict__ w1b,
    const float* __restrict__ l1b, u16* __restrict__ inner,
    int K, int e)
{
    __shared__ __align__(16) u16 lA[128 * 64];
    __shared__ __align__(16) u16 lB[128 * 64];
    const int tid  = threadIdx.x;
    const int lane = tid & 63;
    const int w    = tid >> 6;
    const int wr   = w >> 1, wc = w & 1;
    const int bm = blockIdx.y, bn = blockIdx.x;

    f32x4 acc[4][4] = {};

    const int srow = (lane >> 3);
    const int soff = ((lane & 7) ^ srow) * 8;

    for (int kt = 0; kt < K; kt += 64) {
#pragma unroll
        for (int i = 0; i < 4; ++i) {
            const int c   = w * 4 + i;
            const int row = c * 8 + srow;
            const int rl  = bm * 128 + row;
            const int g   = ((rl >> 10) << 12) + (e << 10) + (rl & 1023);
            async16(h + (size_t)g * DD + kt + soff, &lA[c * 512]);
        }
#pragma unroll
        for (int i = 0; i < 4; ++i) {
            const int c   = w * 4 + i;
            const int row = c * 8 + srow;
            async16(w1b + (size_t)(bn * 128 + row) * DD + kt + soff, &lB[c * 512]);
        }
        __syncthreads();
#pragma unroll
        for (int kk = 0; kk < 2; ++kk) {
            const int sg = ((kk * 4 + (lane >> 4)) ^ (lane & 7)) * 8;
            bf16x8 af[4], bq[4];
#pragma unroll
            for (int i = 0; i < 4; ++i)
                af[i] = *(const bf16x8*)&lA[(wr * 64 + i * 16 + (lane & 15)) * 64 + sg];
#pragma unroll
            for (int i = 0; i < 4; ++i)
                bq[i] = *(const bf16x8*)&lB[(wc * 64 + i * 16 + (lane & 15)) * 64 + sg];
#pragma unroll
            for (int mi = 0; mi < 4; ++mi)
#pragma unroll
                for (int ni = 0; ni < 4; ++ni)
                    acc[mi][ni] = __builtin_amdgcn_mfma_f32_16x16x32_bf16(
                        af[mi], bq[ni], acc[mi][ni], 0, 0, 0);
        }
        __syncthreads();
    }

    const int cbase = bn * 128 + wc * 64 + (lane & 15);
    const int rbase = bm * 128 + wr * 64 + (lane >> 4) * 4;
#pragma unroll
    for (int ni = 0; ni < 4; ++ni) {
        const int col = cbase + ni * 16;
        const float bias = l1b[col];
#pragma unroll
        for (int mi = 0; mi < 4; ++mi) {
            const int r0 = rbase + mi * 16;
#pragma unroll
            for (int r = 0; r < 4; ++r)
                inner[(size_t)(r0 + r) * NINNER + col] = f2bf(gelu_f(acc[mi][ni][r] + bias));
        }
    }
}

// ============ 256x256 8-wave 8-PHASE GEMM1 (faithful m201 template port) ============
// 2 K-tiles per iteration (b0=even tile, b1=odd tile). Phase = {ds_read subtile ||
// issue half-tile stage -> barrier -> lgkmcnt(0) -> setprio(1) -> 16 MFMA ->
// setprio(0) -> [vmcnt(4) at ph4/ph8] -> barrier}.
// Stage slots (verified ledger, 2 async16 per wave per half-tile):
//  ph1: b1.A1(t1)  ph2: b1.B1(t1)  ph3: b0.A0(t+2)  ph4: b0.B0(t+2)
//  ph5: b0.A1+b0.B1(t+2)  ph6: -  ph7: b1.A0(t+3)  ph8: b1.B0(t+3)
// Gates vmcnt(4) at ph4/ph8: every half-tile confirmed >=1 phase before first read;
// slots overwritten only after last read; 4 loads always in flight (never drained).
// B-frags persist in regs across phases (bq0=B-half0, bq1=B-half1): 24 ds_read/K-tile.
#define PH_MID() do { __builtin_amdgcn_s_barrier();                         \
                      asm volatile("s_waitcnt lgkmcnt(0)" ::: "memory");    \
                      __builtin_amdgcn_sched_barrier(0);                    \
                      __builtin_amdgcn_s_setprio(1); } while (0)
#define PH_END() do { __builtin_amdgcn_s_setprio(0);                        \
                      asm volatile("" ::: "memory");                        \
                      __builtin_amdgcn_s_barrier(); } while (0)
#define PH_END_GATE() do { __builtin_amdgcn_s_setprio(0);                   \
                      asm volatile("s_waitcnt vmcnt(4)" ::: "memory");      \
                      __builtin_amdgcn_s_barrier(); } while (0)

__global__ __launch_bounds__(512, 2) void gemm1_8p(
    const u16* __restrict__ h, const u16* __restrict__ w1b,
    const float* __restrict__ l1b, u16* __restrict__ inner,
    int K, int e)
{
    __shared__ __align__(16) u16 lA[2][2][8192];   // [buf][half][128*64]
    __shared__ __align__(16) u16 lB[2][2][8192];
    const int tid  = threadIdx.x;
    const int lane = tid & 63;
    const int w    = tid >> 6;          // 0..7
    const int qr   = w >> 2;            // 0..1
    const int qc   = w & 3;             // 0..3
    const int l15  = lane & 15, l4g = lane >> 4, l7 = lane & 7;
    const int lrow = lane >> 3;
    const int soff = (l7 ^ lrow) * 8;

    // XCD-chunked swizzle over 512 blocks (32 bm x 16 bn)
    const int id  = blockIdx.x;
    const int swz = (id & 7) * 64 + (id >> 3);
    const int bm  = swz >> 4, bn = swz & 15;

    const int NT = K >> 6;              // 16 (e=0) or 8 (e=1) — always even
    const int NI = NT >> 1;

    // loop-invariant stage source offsets (u16 index); add kt at issue
    size_t aOff[2][2], bOff[2][2];
#pragma unroll
    for (int hf = 0; hf < 2; ++hf)
#pragma unroll
        for (int i = 0; i < 2; ++i) {
            const int c  = i * 8 + w;
            const int rl = bm * 256 + hf * 128 + c * 8 + lrow;
            const int g  = ((rl >> 10) << 12) + (e << 10) + (rl & 1023);
            aOff[hf][i]  = (size_t)g * DD + soff;
            const int rb = bn * 256 + hf * 128 + c * 8 + lrow;
            bOff[hf][i]  = (size_t)rb * DD + soff;
        }

    f32x4 acc[4][4][2] = {};            // [quad mh*2+nh][mi][ni]
    bf16x8 af[4][2], bq0[2][2], bq1[2][2];

    auto STA = [&](int buf, int half, int t) {
        const int kt = t << 6;
        async16(h + aOff[half][0] + kt, &lA[buf][half][w * 512]);
        async16(h + aOff[half][1] + kt, &lA[buf][half][(8 + w) * 512]);
    };
    auto STB = [&](int buf, int half, int t) {
        const int kt = t << 6;
        async16(w1b + bOff[half][0] + kt, &lB[buf][half][w * 512]);
        async16(w1b + bOff[half][1] + kt, &lB[buf][half][(8 + w) * 512]);
    };
    auto DSA = [&](int buf, int half) {
#pragma unroll
        for (int mi = 0; mi < 4; ++mi)
#pragma unroll
            for (int kk = 0; kk < 2; ++kk)
                af[mi][kk] = *(const bf16x8*)&lA[buf][half]
                    [(qr * 64 + mi * 16 + l15) * 64 + ((kk * 4 + l4g) ^ l7) * 8];
    };
    auto DSB = [&](int buf, int half, bf16x8 (&bq)[2][2]) {
#pragma unroll
        for (int ni = 0; ni < 2; ++ni)
#pragma unroll
            for (int kk = 0; kk < 2; ++kk)
                bq[ni][kk] = *(const bf16x8*)&lB[buf][half]
                    [(qc * 32 + ni * 16 + l15) * 64 + ((kk * 4 + l4g) ^ l7) * 8];
    };
    auto MM = [&](int q, bf16x8 (&bq)[2][2]) {
#pragma unroll
        for (int mi = 0; mi < 4; ++mi)
#pragma unroll
            for (int ni = 0; ni < 2; ++ni) {
                f32x4 c = acc[q][mi][ni];
                c = __builtin_amdgcn_mfma_f32_16x16x32_bf16(af[mi][0], bq[ni][0], c, 0, 0, 0);
                c = __builtin_amdgcn_mfma_f32_16x16x32_bf16(af[mi][1], bq[ni][1], c, 0, 0, 0);
                acc[q][mi][ni] = c;
            }
    };

    // prologue: b0 fully (tile 0) + b1.A0,B0 (tile 1); retire all of b0, keep 4 in flight
    STA(0, 0, 0); STB(0, 0, 0); STA(0, 1, 0); STB(0, 1, 0);
    STA(1, 0, 1); STB(1, 0, 1);
    asm volatile("s_waitcnt vmcnt(4)" ::: "memory");
    BARRIER();

    for (int i = 0; i < NI; ++i) {
        const int t1  = 2 * i + 1;
        const int tn0 = (2 * i + 2 < NT) ? 2 * i + 2 : NT - 1;   // tail: dead re-stage
        const int tn1 = (2 * i + 3 < NT) ? 2 * i + 3 : NT - 1;
        // ph1: tile t quad(0,0)
        DSA(0, 0); DSB(0, 0, bq0); STA(1, 1, t1);
        PH_MID(); MM(0, bq0); PH_END();
        // ph2: quad(0,1)
        DSB(0, 1, bq1); STB(1, 1, t1);
        PH_MID(); MM(1, bq1); PH_END();
        // ph3: quad(1,0)
        DSA(0, 1); STA(0, 0, tn0);
        PH_MID(); MM(2, bq0); PH_END();
        // ph4: quad(1,1) + GATE
        STB(0, 0, tn0);
        PH_MID(); MM(3, bq1); PH_END_GATE();
        // ph5: tile t+1 quad(0,0)
        DSA(1, 0); DSB(1, 0, bq0); STA(0, 1, tn0); STB(0, 1, tn0);
        PH_MID(); MM(0, bq0); PH_END();
        // ph6: quad(0,1)
        DSB(1, 1, bq1);
        PH_MID(); MM(1, bq1); PH_END();
        // ph7: quad(1,0)
        DSA(1, 1); STA(1, 0, tn1);
        PH_MID(); MM(2, bq0); PH_END();
        // ph8: quad(1,1) + GATE
        STB(1, 0, tn1);
        PH_MID(); MM(3, bq1); PH_END_GATE();
    }

    // epilogue: bias + GELU -> bf16
#pragma unroll
    for (int nh = 0; nh < 2; ++nh) {
#pragma unroll
        for (int ni = 0; ni < 2; ++ni) {
            const int col  = bn * 256 + nh * 128 + qc * 32 + ni * 16 + l15;
            const float bias = l1b[col];
#pragma unroll
            for (int mh = 0; mh < 2; ++mh) {
                const int rb = bm * 256 + mh * 128 + qr * 64 + l4g * 4;
#pragma unroll
                for (int mi = 0; mi < 4; ++mi) {
#pragma unroll
                    for (int r = 0; r < 4; ++r) {
                        const float vv = acc[mh * 2 + nh][mi][ni][r] + bias;
                        inner[(size_t)(rb + mi * 16 + r) * NINNER + col] = f2bf(gelu_f(vv));
                    }
                }
            }
        }
    }
}

// ============== GEMM2: full-K, NO atomics, block owns its output tile ==============
template<int BM, int NBUF>
__global__ __launch_bounds__(BM * 2, 2) void gemm2_nk(
    const u16* __restrict__ inner, const u16* __restrict__ w2b,
    const float* __restrict__ rp, const float* __restrict__ alphap,
    float* __restrict__ out, int e, int lgBn)
{
    constexpr int WAVES = BM / 32;          // 8 / 4 / 2
    constexpr int LB    = 512 / BM;         // B loads per wave: 2 / 4 / 8
    constexpr int NT    = NINNER / 64;      // 64 K-tiles (K always 4096)

    __shared__ __align__(16) u16 lA[NBUF][BM * 64];
    __shared__ __align__(16) u16 lB[NBUF][128 * 64];

    const int tid  = threadIdx.x;
    const int lane = tid & 63;
    const int w    = tid >> 6;
    const int wr   = w >> 1, wc = w & 1;    // wave grid (WAVES/2) x 2, 64x64 each
    const int l15  = lane & 15, l4g = lane >> 4, l7 = lane & 7;
    const int lrow = lane >> 3;
    const int soff = (l7 ^ lrow) * 8;

    const int id  = blockIdx.x;
    const int xcd = id & 7, j = id >> 3;
    const int bm  = ((j >> lgBn) << 3) | xcd;
    const int bn  = j & ((1 << lgBn) - 1);

    size_t aOff[4], bOff[LB];
#pragma unroll
    for (int i = 0; i < 4; ++i) {
        const int row = bm * BM + (i * WAVES + w) * 8 + lrow;
        aOff[i] = (size_t)row * NINNER + soff;
    }
#pragma unroll
    for (int i = 0; i < LB; ++i) {
        const int row = bn * 128 + (i * WAVES + w) * 8 + lrow;
        bOff[i] = (size_t)row * NINNER + soff;
    }

    auto STAGE = [&](int buf, int kt) {
#pragma unroll
        for (int i = 0; i < 4; ++i)
            async16(inner + aOff[i] + kt, &lA[buf][(i * WAVES + w) * 512]);
#pragma unroll
        for (int i = 0; i < LB; ++i)
            async16(w2b + bOff[i] + kt, &lB[buf][(i * WAVES + w) * 512]);
    };

    f32x4 acc[4][4] = {};
    bf16x8 af[4][2], bq[4][2];

    // prologue
    STAGE(0, 0);
    if constexpr (NBUF == 3) STAGE(1, 64);
    if constexpr (BM == 256)      asm volatile("s_waitcnt vmcnt(6)"  ::: "memory");
    else if constexpr (BM == 64)  asm volatile("s_waitcnt vmcnt(12)" ::: "memory");
    else                          asm volatile("s_waitcnt vmcnt(0)"  ::: "memory");
    BARRIER();

    int cur = 0, stg = NBUF - 1;
    for (int t = 0; t < NT; ++t) {
        const int ts = (t + NBUF - 1 < NT ? t + NBUF - 1 : NT - 1);
        STAGE(stg, ts * 64);
#pragma unroll
        for (int mi = 0; mi < 4; ++mi)
#pragma unroll
            for (int kk = 0; kk < 2; ++kk)
                af[mi][kk] = *(const bf16x8*)&lA[cur]
                    [(wr * 64 + mi * 16 + l15) * 64 + ((kk * 4 + l4g) ^ l7) * 8];
#pragma unroll
        for (int ni = 0; ni < 4; ++ni)
#pragma unroll
            for (int kk = 0; kk < 2; ++kk)
                bq[ni][kk] = *(const bf16x8*)&lB[cur]
                    [(wc * 64 + ni * 16 + l15) * 64 + ((kk * 4 + l4g) ^ l7) * 8];
        __builtin_amdgcn_s_setprio(1);
#pragma unroll
        for (int mi = 0; mi < 4; ++mi)
#pragma unroll
            for (int ni = 0; ni < 4; ++ni) {
                f32x4 c = acc[mi][ni];
                c = __builtin_amdgcn_mfma_f32_16x16x32_bf16(af[mi][0], bq[ni][0], c, 0, 0, 0);
                c = __builtin_amdgcn_mfma_f32_16x16x32_bf16(af[mi][1], bq[ni][1], c, 0, 0, 0);
                acc[mi][ni] = c;
            }
        __builtin_amdgcn_s_setprio(0);
        if constexpr (BM == 256)      asm volatile("s_waitcnt vmcnt(6)"  ::: "memory");
        else if constexpr (BM == 64)  asm volatile("s_waitcnt vmcnt(12)" ::: "memory");
        else                          asm volatile("s_waitcnt vmcnt(0)"  ::: "memory");
        BARRIER();
        cur = (cur + 1 == NBUF) ? 0 : cur + 1;
        stg = (stg + 1 == NBUF) ? 0 : stg + 1;
    }

    // epilogue: plain RMW (exclusive tile ownership — no atomics)
    const float alpha = alphap[0];
#pragma unroll
    for (int mi = 0; mi < 4; ++mi) {
#pragma unroll
        for (int r = 0; r < 4; ++r) {
            const int rl = bm * BM + wr * 64 + mi * 16 + l4g * 4 + r;
            const int g  = ((rl >> 10) << 12) + (e << 10) + (rl & 1023);
            const float sc = alpha * rp[(size_t)g * 4 + e] + 1.0f;
            float* po = out + (size_t)g * DD;
#pragma unroll
            for (int ni = 0; ni < 4; ++ni) {
                const int col = bn * 128 + wc * 64 + ni * 16 + l15;
                po[col] += sc * acc[mi][ni][r];
            }
        }
    }
}

extern "C" void kernel_launch(void* const* d_in, const int* in_sizes, int n_in,
                              void* d_out, int out_size, void* d_ws, size_t ws_size,
                              hipStream_t stream) {
    const float* x     = (const float*)d_in[0];
    const float* rp    = (const float*)d_in[1];
    const float* alpha = (const float*)d_in[2];
    const float* nw    = (const float*)d_in[3];
    const float* nb    = (const float*)d_in[4];
    const float* l1w   = (const float*)d_in[5];
    const float* l1b   = (const float*)d_in[6];
    const float* l2w   = (const float*)d_in[7];
    const float* l2b   = (const float*)d_in[8];
    float* out = (float*)d_out;

    // workspace layout: h (64MB) | inner (64MB) | w1b (8MB) | w2b (8MB)
    char* ws = (char*)d_ws;
    if (ws_size < ((size_t)144 << 20)) return;
    u16* h     = (u16*)(ws);
    u16* inner = (u16*)(ws + ((size_t)64 << 20));
    u16* w1b   = (u16*)(ws + ((size_t)128 << 20));
    u16* w2b   = (u16*)(ws + ((size_t)136 << 20));

    cast_w<<<8192, 256, 0, stream>>>(l1w, l2w, w1b, w2b);
    ln_kernel<<<NTOK, 256, 0, stream>>>(x, nw, nb, l2b, rp, alpha, h, out);
    for (int e = 0; e < 4; ++e) {
        const int m = DD >> e;
        if (e < 2)
            gemm1_8p<<<512, 512, 0, stream>>>(h, w1b, l1b, inner, m, e);
        else
            gemm1<<<dim3(NINNER / 128, MROWS / 128), 256, 0, stream>>>(h, w1b, l1b, inner, m, e);
        switch (e) {
            case 0: gemm2_nk<256, 3><<<256, 512, 0, stream>>>(inner, w2b, rp, alpha, out, e, 3); break;
            case 1: gemm2_nk<128, 2><<<256, 256, 0, stream>>>(inner, w2b, rp, alpha, out, e, 2); break;
            case 2: gemm2_nk< 64, 3><<<256, 128, 0, stream>>>(inner, w2b, rp, alpha, out, e, 1); break;
            case 3: gemm2_nk< 64, 3><<<128, 128, 0, stream>>>(inner, w2b, rp, alpha, out, e, 0); break;
        }
    }
}